// Round 10
// baseline (175.277 us; speedup 1.0000x reference)
//
#include <hip/hip_runtime.h>
#include <hip/hip_bf16.h>

#define BD 4
#define CD 96
#define OD 96
#define HD 128
#define WD 128
#define HWD (HD*WD)          // 16384

typedef __attribute__((ext_vector_type(8))) short bfrag;   // 8 bf16 (4 VGPRs)
typedef __attribute__((ext_vector_type(4))) float ffrag;   // 4 fp32 acc

__device__ __forceinline__ short f2bs(float f) {
    __hip_bfloat16 h = __float2bfloat16(f);
    return *reinterpret_cast<short*>(&h);
}

// XCD-aware swizzle for 512-block launches (round-robin dispatch over 8 XCDs):
// XCD k owns 64 consecutive logical blocks = 64 image rows.
__device__ __forceinline__ int swizzle512(int gid) {
    return ((gid & 7) << 6) | (gid >> 3);
}

// ---------------------------------------------------------------------------
// k_prep: fused transpose + weight repack (one launch, 580 blocks).
//  blocks [0,256): x (NCHW fp32) -> xb16 (NHWC bf16)   [256 blocks = B*HW/256]
//  blocks [256,580): weights -> bf16 MFMA B-frag layouts (k = tap*96+c)
//   order: w[((s*NT+nt)*64 + l)*8 + j] = B[k=32s+(l>>4)*8+j][o=16nt+(l&15)]
// ---------------------------------------------------------------------------
__global__ __launch_bounds__(256) void k_prep(const float* __restrict__ x,
                                              const float* __restrict__ dconv_w,
                                              const float* __restrict__ off_w,
                                              const float* __restrict__ def_w,
                                              short* __restrict__ xb16,
                                              short* __restrict__ wB1,
                                              short* __restrict__ wB2,
                                              short* __restrict__ wB) {
    __shared__ short tile[256 * 104];
    int tid = threadIdx.x;
    if (blockIdx.x < 256) {
        int pix0 = blockIdx.x * 256;
        int b = pix0 / HWD; int hw0 = pix0 % HWD;
        for (int e = tid; e < 96*64; e += 256) {
            int c = e >> 6, g = e & 63;
            float4 v = *(const float4*)(x + ((size_t)(b*96 + c))*HWD + hw0 + 4*g);
            tile[(4*g+0)*104 + c] = f2bs(v.x);
            tile[(4*g+1)*104 + c] = f2bs(v.y);
            tile[(4*g+2)*104 + c] = f2bs(v.z);
            tile[(4*g+3)*104 + c] = f2bs(v.w);
        }
        __syncthreads();
        for (int e = tid; e < 256*12; e += 256) {
            int px = e / 12, c8 = e % 12;
            bfrag v = *(const bfrag*)(tile + px*104 + c8*8);
            *(bfrag*)(xb16 + ((size_t)(pix0 + px))*96 + c8*8) = v;
        }
    } else {
        int t = (blockIdx.x - 256) * 256 + tid;
        if (t < 27648) {              // 864 x 32, NT=2
            int j = t & 7; int l = (t >> 3) & 63; int tl = t >> 9;
            int s = tl >> 1, nt = tl & 1;
            int k = 32*s + (l >> 4)*8 + j;
            int o = 16*nt + (l & 15);
            int c = k % 96, tap = k / 96;
            wB2[t] = (o < 18) ? f2bs(off_w[(o*96 + c)*9 + tap]) : (short)0;
        }
        if (t < 82944) {              // 864 x 96, NT=6
            int j = t & 7; int l = (t >> 3) & 63; int tl = t >> 9;
            int s = tl / 6, nt = tl % 6;
            int k = 32*s + (l >> 4)*8 + j;
            int o = 16*nt + (l & 15);
            int c = k % 96, tap = k / 96;
            wB1[t] = f2bs(dconv_w[(o*96 + c)*9 + tap]);
            wB[t]  = f2bs(def_w [(o*96 + c)*9 + tap]);
        }
    }
}

// ---------------------------------------------------------------------------
// Kernel 1 (M=32/wave, software-pipelined): x3b = bf16(x + relu(conv dil2))
// Flat s-loop (unroll 3): consume frags issued at s-1, issue s+1.
// ---------------------------------------------------------------------------
__global__ __launch_bounds__(256, 2) void k_conv1(const float* __restrict__ x,
                                                  const short* __restrict__ xb16,
                                                  const short* __restrict__ wB,
                                                  const float* __restrict__ bias,
                                                  short* __restrict__ x3b) {
    int pix0 = swizzle512(blockIdx.x) * 128;
    int b = pix0 / HWD; int hw0 = pix0 % HWD;
    int h = hw0 / WD;
    int tid = threadIdx.x;
    int l = tid & 63, wv = tid >> 6;
    int q = l >> 4, mr = l & 15;
    int wq = 32*wv;
    const short* xb = xb16 + ((size_t)b * HWD) * 96;
    const bfrag az = {0,0,0,0,0,0,0,0};

    auto aoff = [&](int tap, int mt, bool* vv) -> int {
        int ty = tap/3, tx = tap - 3*(tap/3);
        int y  = h + ty*2 - 2;
        int xx = wq + 16*mt + mr + tx*2 - 2;
        bool vy = (unsigned)y < HD, vx = (unsigned)xx < WD;
        *vv = vy && vx;
        int yc = min(max(y,0),HD-1), xc = min(max(xx,0),WD-1);
        return (yc*WD + xc)*96 + q*8;
    };

    ffrag acc[2][6];
    #pragma unroll
    for (int mt = 0; mt < 2; mt++)
        #pragma unroll
        for (int nt = 0; nt < 6; nt++) acc[mt][nt] = ffrag{0.f,0.f,0.f,0.f};

    int aoC[2], aoN[2]; bool vC[2], vN[2];
    bfrag gA[2], gIn[2], bA[6], bIn[6];

    #pragma unroll
    for (int mt = 0; mt < 2; mt++) aoC[mt] = aoff(0, mt, &vC[mt]);
    #pragma unroll
    for (int mt = 0; mt < 2; mt++) gA[mt] = *(const bfrag*)(xb + aoC[mt]);
    #pragma unroll
    for (int nt = 0; nt < 6; nt++) bA[nt] = *(const bfrag*)(wB + ((size_t)nt*64 + l)*8);

    #pragma unroll 3
    for (int s = 0; s < 27; s++) {
        int tap = s / 3, sc = s - 3*tap;
        if (sc == 0) {
            int tn = tap + 1; if (tn > 8) tn = 8;
            #pragma unroll
            for (int mt = 0; mt < 2; mt++) aoN[mt] = aoff(tn, mt, &vN[mt]);
        }
        #pragma unroll
        for (int mt = 0; mt < 2; mt++) {
            int off = (sc < 2) ? (aoC[mt] + (sc+1)*32) : aoN[mt];
            gIn[mt] = *(const bfrag*)(xb + off);
        }
        int sn = s + 1; if (sn > 26) sn = 26;
        #pragma unroll
        for (int nt = 0; nt < 6; nt++)
            bIn[nt] = *(const bfrag*)(wB + ((size_t)(sn*6 + nt)*64 + l)*8);
        #pragma unroll
        for (int mt = 0; mt < 2; mt++) {
            bfrag a = gA[mt];
            if (!vC[mt]) a = az;
            #pragma unroll
            for (int nt = 0; nt < 6; nt++)
                acc[mt][nt] = __builtin_amdgcn_mfma_f32_16x16x32_bf16(a, bA[nt], acc[mt][nt], 0, 0, 0);
        }
        #pragma unroll
        for (int mt = 0; mt < 2; mt++) gA[mt] = gIn[mt];
        #pragma unroll
        for (int nt = 0; nt < 6; nt++) bA[nt] = bIn[nt];
        if (sc == 2) {
            #pragma unroll
            for (int mt = 0; mt < 2; mt++) { aoC[mt] = aoN[mt]; vC[mt] = vN[mt]; }
        }
    }

    #pragma unroll
    for (int mt = 0; mt < 2; mt++) {
        int hwb = hw0 + wq + 16*mt + q*4;
        #pragma unroll
        for (int nt = 0; nt < 6; nt++) {
            int o = 16*nt + mr;
            float bo = bias[o];
            float4 xr = *(const float4*)(x + ((size_t)(b*96 + o))*HWD + hwb);
            short* op = x3b + ((size_t)(b*HWD + hwb))*96 + o;
            op[0]   = f2bs(xr.x + fmaxf(acc[mt][nt][0] + bo, 0.f));
            op[96]  = f2bs(xr.y + fmaxf(acc[mt][nt][1] + bo, 0.f));
            op[192] = f2bs(xr.z + fmaxf(acc[mt][nt][2] + bo, 0.f));
            op[288] = f2bs(xr.w + fmaxf(acc[mt][nt][3] + bo, 0.f));
        }
    }
}

// ---------------------------------------------------------------------------
// Kernel 2 (fused, M=32/wave, software-pipelined): conv2-MFMA -> offsets
// (LDS, no barriers) -> bilinear gather -> deform MFMA -> out.
// ---------------------------------------------------------------------------
__global__ __launch_bounds__(256, 2) void k_deform(const short* __restrict__ x3b,
                                                   const short* __restrict__ wB2,
                                                   const float* __restrict__ off_b,
                                                   const short* __restrict__ wB,
                                                   const float* __restrict__ def_b,
                                                   float* __restrict__ out) {
    __shared__ float offsb[128][20];

    int pix0 = swizzle512(blockIdx.x) * 128;
    int b = pix0 / HWD; int hw0 = pix0 % HWD;
    int h = hw0 / WD;
    int tid = threadIdx.x;
    int l = tid & 63, wv = tid >> 6;
    int q = l >> 4, mr = l & 15;
    int wq = 32*wv;
    const short* xb = x3b + ((size_t)b * HWD) * 96;
    const bfrag az = {0,0,0,0,0,0,0,0};

    // ======== Phase 1: conv2 via pipelined MFMA -> offsb ========
    {
        auto aoff2 = [&](int tap, int mt, bool* vv) -> int {
            int ty = tap/3, tx = tap - 3*(tap/3);
            int y  = h + ty - 1;
            int xx = wq + 16*mt + mr + tx - 1;
            bool vy = (unsigned)y < HD, vx = (unsigned)xx < WD;
            *vv = vy && vx;
            int yc = min(max(y,0),HD-1), xc = min(max(xx,0),WD-1);
            return (yc*WD + xc)*96 + q*8;
        };

        ffrag oa[2][2];
        #pragma unroll
        for (int mt = 0; mt < 2; mt++)
            #pragma unroll
            for (int nt = 0; nt < 2; nt++) oa[mt][nt] = ffrag{0.f,0.f,0.f,0.f};

        int aoC[2], aoN[2]; bool vC[2], vN[2];
        bfrag gA[2], gIn[2], bA[2], bIn[2];

        #pragma unroll
        for (int mt = 0; mt < 2; mt++) aoC[mt] = aoff2(0, mt, &vC[mt]);
        #pragma unroll
        for (int mt = 0; mt < 2; mt++) gA[mt] = *(const bfrag*)(xb + aoC[mt]);
        #pragma unroll
        for (int nt = 0; nt < 2; nt++) bA[nt] = *(const bfrag*)(wB2 + ((size_t)nt*64 + l)*8);

        #pragma unroll 3
        for (int s = 0; s < 27; s++) {
            int tap = s / 3, sc = s - 3*tap;
            if (sc == 0) {
                int tn = tap + 1; if (tn > 8) tn = 8;
                #pragma unroll
                for (int mt = 0; mt < 2; mt++) aoN[mt] = aoff2(tn, mt, &vN[mt]);
            }
            #pragma unroll
            for (int mt = 0; mt < 2; mt++) {
                int off = (sc < 2) ? (aoC[mt] + (sc+1)*32) : aoN[mt];
                gIn[mt] = *(const bfrag*)(xb + off);
            }
            int sn = s + 1; if (sn > 26) sn = 26;
            #pragma unroll
            for (int nt = 0; nt < 2; nt++)
                bIn[nt] = *(const bfrag*)(wB2 + ((size_t)(sn*2 + nt)*64 + l)*8);
            #pragma unroll
            for (int mt = 0; mt < 2; mt++) {
                bfrag a = gA[mt];
                if (!vC[mt]) a = az;
                oa[mt][0] = __builtin_amdgcn_mfma_f32_16x16x32_bf16(a, bA[0], oa[mt][0], 0, 0, 0);
                oa[mt][1] = __builtin_amdgcn_mfma_f32_16x16x32_bf16(a, bA[1], oa[mt][1], 0, 0, 0);
            }
            #pragma unroll
            for (int mt = 0; mt < 2; mt++) gA[mt] = gIn[mt];
            #pragma unroll
            for (int nt = 0; nt < 2; nt++) bA[nt] = bIn[nt];
            if (sc == 2) {
                #pragma unroll
                for (int mt = 0; mt < 2; mt++) { aoC[mt] = aoN[mt]; vC[mt] = vN[mt]; }
            }
        }
        #pragma unroll
        for (int mt = 0; mt < 2; mt++) {
            int row = wq + 16*mt + q*4;
            float bo0 = off_b[mr];
            #pragma unroll
            for (int r = 0; r < 4; r++) offsb[row + r][mr] = oa[mt][0][r] + bo0;
            if (mr < 2) {
                float bo1 = off_b[16 + mr];
                #pragma unroll
                for (int r = 0; r < 4; r++) offsb[row + r][16 + mr] = oa[mt][1][r] + bo1;
            }
        }
    }
    // no __syncthreads: offsb rows wq..wq+31 produced & consumed by wave wv

    // ======== Phase 2: pipelined gather + deform MFMA ========
    auto mkptr = [&](int tap, float dy, float dx, int wp, float* fo, int* oo) {
        int ty = tap/3, tx = tap - 3*(tap/3);
        float py  = (float)(h + ty - 1) + dy;
        float pxf = (float)(wp + tx - 1) + dx;
        float y0f = floorf(py), x0f = floorf(pxf);
        float wy = py - y0f, wx = pxf - x0f;
        int y0 = (int)y0f, x0 = (int)x0f;
        int y1 = y0 + 1, x1 = x0 + 1;
        bool vy0 = (unsigned)y0 < HD, vy1 = (unsigned)y1 < HD;
        bool vx0 = (unsigned)x0 < WD, vx1 = (unsigned)x1 < WD;
        fo[0] = (vy0 && vx0) ? (1.f-wy)*(1.f-wx) : 0.f;
        fo[1] = (vy0 && vx1) ? (1.f-wy)*wx       : 0.f;
        fo[2] = (vy1 && vx0) ? wy*(1.f-wx)       : 0.f;
        fo[3] = (vy1 && vx1) ? wy*wx             : 0.f;
        int yc0 = min(max(y0,0),HD-1), yc1 = min(max(y1,0),HD-1);
        int xc0 = min(max(x0,0),WD-1), xc1 = min(max(x1,0),WD-1);
        oo[0] = (yc0*WD + xc0)*96 + q*8;
        oo[1] = (yc0*WD + xc1)*96 + q*8;
        oo[2] = (yc1*WD + xc0)*96 + q*8;
        oo[3] = (yc1*WD + xc1)*96 + q*8;
    };

    ffrag acc[2][6];
    #pragma unroll
    for (int mt = 0; mt < 2; mt++)
        #pragma unroll
        for (int nt = 0; nt < 6; nt++) acc[mt][nt] = ffrag{0.f,0.f,0.f,0.f};

    float fbv[2][4], fbn[2][4], dyn[2], dxn[2];
    int po[2][4], pon[2][4];
    bfrag g[2][4], gin[2][4], bA[6], bIn[6];

    #pragma unroll
    for (int mt = 0; mt < 2; mt++) {
        int wp = wq + 16*mt + mr;
        mkptr(0, offsb[wp][0], offsb[wp][1], wp, fbv[mt], po[mt]);
    }
    #pragma unroll
    for (int mt = 0; mt < 2; mt++)
        #pragma unroll
        for (int c = 0; c < 4; c++) g[mt][c] = *(const bfrag*)(xb + po[mt][c]);
    #pragma unroll
    for (int nt = 0; nt < 6; nt++) bA[nt] = *(const bfrag*)(wB + ((size_t)nt*64 + l)*8);

    #pragma unroll 3
    for (int s = 0; s < 27; s++) {
        int tap = s / 3, sc = s - 3*tap;
        if (sc == 0) {
            int tn = tap + 1; if (tn > 8) tn = 8;
            #pragma unroll
            for (int mt = 0; mt < 2; mt++) {
                int wp = wq + 16*mt + mr;
                dyn[mt] = offsb[wp][2*tn];
                dxn[mt] = offsb[wp][2*tn + 1];
            }
        }
        if (sc == 1) {
            int tn = tap + 1; if (tn > 8) tn = 8;
            #pragma unroll
            for (int mt = 0; mt < 2; mt++)
                mkptr(tn, dyn[mt], dxn[mt], wq + 16*mt + mr, fbn[mt], pon[mt]);
        }
        #pragma unroll
        for (int mt = 0; mt < 2; mt++)
            #pragma unroll
            for (int c = 0; c < 4; c++) {
                int off = (sc < 2) ? (po[mt][c] + (sc+1)*32) : pon[mt][c];
                gin[mt][c] = *(const bfrag*)(xb + off);
            }
        int sn = s + 1; if (sn > 26) sn = 26;
        #pragma unroll
        for (int nt = 0; nt < 6; nt++)
            bIn[nt] = *(const bfrag*)(wB + ((size_t)(sn*6 + nt)*64 + l)*8);

        #pragma unroll
        for (int mt = 0; mt < 2; mt++) {
            const int* i00 = (const int*)&g[mt][0];
            const int* i01 = (const int*)&g[mt][1];
            const int* i10 = (const int*)&g[mt][2];
            const int* i11 = (const int*)&g[mt][3];
            float f00 = fbv[mt][0], f01 = fbv[mt][1];
            float f10 = fbv[mt][2], f11 = fbv[mt][3];
            int ap[4];
            #pragma unroll
            for (int d = 0; d < 4; d++) {
                float a0 = __int_as_float(((unsigned)i00[d]) << 16);
                float b0f = __int_as_float(((unsigned)i01[d]) << 16);
                float c0f = __int_as_float(((unsigned)i10[d]) << 16);
                float d0 = __int_as_float(((unsigned)i11[d]) << 16);
                float a1 = __int_as_float(i00[d] & 0xffff0000);
                float b1f = __int_as_float(i01[d] & 0xffff0000);
                float c1f = __int_as_float(i10[d] & 0xffff0000);
                float d1 = __int_as_float(i11[d] & 0xffff0000);
                float rlo = f00*a0 + f01*b0f + f10*c0f + f11*d0;
                float rhi = f00*a1 + f01*b1f + f10*c1f + f11*d1;
                ap[d] = (int)((unsigned short)f2bs(rlo)) |
                        ((int)((unsigned short)f2bs(rhi)) << 16);
            }
            bfrag a = *(const bfrag*)ap;
            #pragma unroll
            for (int nt = 0; nt < 6; nt++)
                acc[mt][nt] = __builtin_amdgcn_mfma_f32_16x16x32_bf16(a, bA[nt], acc[mt][nt], 0, 0, 0);
        }
        #pragma unroll
        for (int mt = 0; mt < 2; mt++)
            #pragma unroll
            for (int c = 0; c < 4; c++) g[mt][c] = gin[mt][c];
        #pragma unroll
        for (int nt = 0; nt < 6; nt++) bA[nt] = bIn[nt];
        if (sc == 2) {
            #pragma unroll
            for (int mt = 0; mt < 2; mt++)
                #pragma unroll
                for (int c = 0; c < 4; c++) { po[mt][c] = pon[mt][c]; fbv[mt][c] = fbn[mt][c]; }
        }
    }

    // ---- epilogue: NCHW fp32 out ----
    #pragma unroll
    for (int mt = 0; mt < 2; mt++) {
        int hwb = hw0 + wq + 16*mt + q*4;
        #pragma unroll
        for (int nt = 0; nt < 6; nt++) {
            int o = 16*nt + mr;
            float bo = def_b[o];
            float4 v;
            v.x = acc[mt][nt][0] + bo; v.y = acc[mt][nt][1] + bo;
            v.z = acc[mt][nt][2] + bo; v.w = acc[mt][nt][3] + bo;
            *(float4*)(out + ((size_t)(b*96 + o))*HWD + hwb) = v;
        }
    }
}

// ---------------------------------------------------------------------------
// Workspace layout (bytes):
//   xb16 : 0        .. 12582912   (B*HW*96 bf16, NHWC of x)
//   x3b  : 12582912 .. 25165824   (B*HW*96 bf16, NHWC of x3)
//   wB1  : 25165824 .. 25331712
//   wB2  : 25331712 .. 25387008
//   wB   : 25387008 .. 25552896
// ---------------------------------------------------------------------------
extern "C" void kernel_launch(void* const* d_in, const int* in_sizes, int n_in,
                              void* d_out, int out_size, void* d_ws, size_t ws_size,
                              hipStream_t stream) {
    const float* x       = (const float*)d_in[0];
    const float* dconv_w = (const float*)d_in[1];
    const float* dconv_b = (const float*)d_in[2];
    const float* off_w   = (const float*)d_in[3];
    const float* off_b   = (const float*)d_in[4];
    const float* def_w   = (const float*)d_in[5];
    const float* def_b   = (const float*)d_in[6];
    float* out = (float*)d_out;

    char* ws = (char*)d_ws;
    short* xb16 = (short*)(ws);
    short* x3b  = (short*)(ws + 12582912);
    short* wB1  = (short*)(ws + 25165824);
    short* wB2  = (short*)(ws + 25331712);
    short* wB   = (short*)(ws + 25387008);

    k_prep<<<580, 256, 0, stream>>>(x, dconv_w, off_w, def_w, xb16, wB1, wB2, wB);
    k_conv1<<<(BD*HWD)/128, 256, 0, stream>>>(x, xb16, wB1, dconv_b, x3b);
    k_deform<<<(BD*HWD)/128, 256, 0, stream>>>(x3b, wB2, off_b, wB, def_b, out);
}